// Round 11
// baseline (447.120 us; speedup 1.0000x reference)
//
#include <hip/hip_runtime.h>
#include <hip/hip_bf16.h>
#include <cstdint>
#include <cstddef>

#define BB 2
#define SS 2048
#define EE 1024
#define HH 16
#define DKK 64

typedef __bf16 bf16;
typedef __bf16 bf16x8 __attribute__((ext_vector_type(8)));
typedef float f32x4 __attribute__((ext_vector_type(4)));

__device__ __forceinline__ void ldg2lds16(const void* g, void* l) {
  __builtin_amdgcn_global_load_lds(
      (const __attribute__((address_space(1))) unsigned int*)g,
      (__attribute__((address_space(3))) unsigned int*)l, 16, 0, 0);
}

// ---------------------------------------------------------------------------
// Dtype detector (insurance): fp32 (flag=1) vs packed bf16 (flag=0).
// ---------------------------------------------------------------------------
__global__ __launch_bounds__(256) void detect_kernel(
    const unsigned int* __restrict__ q, int* __restrict__ flag) {
  const int t = threadIdx.x;
  int cnt = 0;
#pragma unroll
  for (int i = 0; i < 4; i++) {
    unsigned int v = q[t * 4 + i];
    unsigned int e = (v >> 7) & 0xFF;
    cnt += (e >= 110 && e <= 140) ? 1 : 0;
  }
  __shared__ int s;
  if (t == 0) s = 0;
  __syncthreads();
  atomicAdd(&s, cnt);
  __syncthreads();
  if (t == 0) *flag = (s < 512) ? 1 : 0;
}

// ---------------------------------------------------------------------------
// Convert prepass: materialize bf16 copies of all 11 float tensors.
// ---------------------------------------------------------------------------
struct ConvArgs {
  const void* src[11];
  void* dst[11];
  int n[11];
};

__global__ __launch_bounds__(256) void convert_kernel(
    ConvArgs a, const int* __restrict__ flag) {
  const int j = blockIdx.y;
  const int n = a.n[j];
  const int i0 = (blockIdx.x * 256 + threadIdx.x) * 8;
  if (i0 >= n) return;
  bf16* d = (bf16*)a.dst[j];
  if (*flag) {
    const float* s = (const float*)a.src[j];
    float4 f0 = ((const float4*)(s + i0))[0];
    float4 f1 = ((const float4*)(s + i0))[1];
    union { bf16 h[8]; uint4 u; } t;
    t.h[0] = (bf16)f0.x; t.h[1] = (bf16)f0.y;
    t.h[2] = (bf16)f0.z; t.h[3] = (bf16)f0.w;
    t.h[4] = (bf16)f1.x; t.h[5] = (bf16)f1.y;
    t.h[6] = (bf16)f1.z; t.h[7] = (bf16)f1.w;
    *(uint4*)(d + i0) = t.u;
  } else {
    uint4 v = *(const uint4*)((const bf16*)a.src[j] + i0);
    *(uint4*)(d + i0) = v;
  }
}

// ---------------------------------------------------------------------------
// Mask summary: per (b, q-tile-128, k-tile-64) -> 1 all-keep / 0 all-mask / 2 mixed
// ---------------------------------------------------------------------------
__global__ __launch_bounds__(256) void mask_summary_kernel(
    const int* __restrict__ mask, unsigned char* __restrict__ msum) {
  const int bid = blockIdx.x;            // b*512 + qt*32 + kt
  const int kt = bid & 31;
  const int qt = (bid >> 5) & 15;
  const int b = bid >> 9;
  const int t = threadIdx.x;
  const int r = t >> 1;
  const int c0 = (t & 1) * 32;
  const int* p = mask + ((size_t)(b * SS + qt * 128 + r)) * SS + kt * 64 + c0;
  bool all1 = true, any1 = false;
#pragma unroll
  for (int i = 0; i < 8; i++) {
    int4 v = ((const int4*)p)[i];
    all1 = all1 && (v.x != 0) && (v.y != 0) && (v.z != 0) && (v.w != 0);
    any1 = any1 || (v.x != 0) || (v.y != 0) || (v.z != 0) || (v.w != 0);
  }
  __shared__ int sall, sany;
  if (t == 0) { sall = 1; sany = 0; }
  __syncthreads();
  if (!all1) atomicAnd(&sall, 0);
  if (any1) atomicOr(&sany, 1);
  __syncthreads();
  if (t == 0) msum[bid] = sall ? 1 : (sany ? 2 : 0);
}

// ---------------------------------------------------------------------------
// bt-GEMM, BK=32 (r6/r7 winner), XOR swizzle.
// mode 0: row-major [M][1024]; mode 1: *0.125*log2e (Q pre-scale for exp2
// softmax); mode 2: transposed V write -> [B][H][DK][S].
// ---------------------------------------------------------------------------
template <int BM, int BN, int WGM, int WGN, typename OutT>
__device__ __forceinline__ void gemm_bt_core(
    const bf16* __restrict__ A, const bf16* __restrict__ W,
    const bf16* __restrict__ bias, OutT* __restrict__ out, int mode) {
  constexpr int BK = 32;
  constexpr int WM = BM / WGM, WN = BN / WGN;
  constexpr int MI = WM / 16, NI = WN / 16;
  constexpr int Kd = 1024, Nd = 1024;

  __shared__ __align__(16) bf16 As[BM * BK];
  __shared__ __align__(16) bf16 Bs[BN * BK];

  const int tid = threadIdx.x;
  const int wid = tid >> 6, lane = tid & 63;
  const int lr = lane & 15, lg = lane >> 4;
  const int wm = (wid / WGN) * WM, wn = (wid % WGN) * WN;
  const int m0 = blockIdx.y * BM, n0 = blockIdx.x * BN;

  f32x4 acc[MI][NI] = {};

  const int sr = tid >> 2;                        // staging row 0..63
  const int scol = ((tid & 3) ^ (sr & 3)) * 8;    // swizzled source chunk
  const int rchunk = (lg ^ (lr & 3)) * 8;         // swizzled read chunk

  for (int k0 = 0; k0 < Kd; k0 += BK) {
#pragma unroll
    for (int i = 0; i < BM / 64; i++)
      ldg2lds16(A + (size_t)(m0 + sr + i * 64) * Kd + k0 + scol,
                &As[(sr + i * 64) * BK + (tid & 3) * 8]);
#pragma unroll
    for (int i = 0; i < BN / 64; i++)
      ldg2lds16(W + (size_t)(n0 + sr + i * 64) * Kd + k0 + scol,
                &Bs[(sr + i * 64) * BK + (tid & 3) * 8]);
    __syncthreads();
    bf16x8 af[MI], bfr[NI];
#pragma unroll
    for (int mi = 0; mi < MI; mi++)
      af[mi] = *(const bf16x8*)&As[(wm + mi * 16 + lr) * BK + rchunk];
#pragma unroll
    for (int ni = 0; ni < NI; ni++)
      bfr[ni] = *(const bf16x8*)&Bs[(wn + ni * 16 + lr) * BK + rchunk];
#pragma unroll
    for (int mi = 0; mi < MI; mi++)
#pragma unroll
      for (int ni = 0; ni < NI; ni++)
        acc[mi][ni] = __builtin_amdgcn_mfma_f32_16x16x32_bf16(
            af[mi], bfr[ni], acc[mi][ni], 0, 0, 0);
    __syncthreads();
  }

  const float scale = (mode == 1) ? 0.180336880111f : 1.0f;  // 0.125*log2(e)

  // C/D layout: col = lane&15 (n), row = (lane>>4)*4 + reg (m)
#pragma unroll
  for (int ni = 0; ni < NI; ni++) {
    const int n = n0 + wn + ni * 16 + lr;
    const float bv = (float)bias[n];
#pragma unroll
    for (int mi = 0; mi < MI; mi++) {
      const int m = m0 + wm + mi * 16 + lg * 4;
      f32x4 v = acc[mi][ni];
      if (mode == 2) {
        const int h = n >> 6, d = n & 63;
        const int b = m >> 11, s0v = m & 2047;
        union { bf16 hh[4]; uint2 u; } tmp;
#pragma unroll
        for (int r = 0; r < 4; r++) tmp.hh[r] = (bf16)(v[r] + bv);
        const size_t idx = (((size_t)b * HH + h) * DKK + d) * SS + s0v;
        *(uint2*)((bf16*)out + idx) = tmp.u;
      } else {
#pragma unroll
        for (int r = 0; r < 4; r++)
          out[(size_t)(m + r) * Nd + n] = (OutT)((v[r] + bv) * scale);
      }
    }
  }
}

__global__ __launch_bounds__(256) void qkv_proj_kernel(
    const bf16* __restrict__ q, const bf16* __restrict__ k,
    const bf16* __restrict__ v, const bf16* __restrict__ Wq,
    const bf16* __restrict__ Wk, const bf16* __restrict__ Wv,
    const bf16* __restrict__ bias4, bf16* __restrict__ Qo,
    bf16* __restrict__ Ko, bf16* __restrict__ Vto) {
  const int z = blockIdx.z;
  const bf16* A = z == 0 ? q : (z == 1 ? k : v);
  const bf16* W = z == 0 ? Wq : (z == 1 ? Wk : Wv);
  const bf16* bi = bias4 + z * 1024;
  bf16* out = z == 0 ? Qo : (z == 1 ? Ko : Vto);
  gemm_bt_core<128, 128, 2, 2, bf16>(A, W, bi, out, z == 0 ? 1 : (z == 1 ? 0 : 2));
}

__global__ __launch_bounds__(256) void o_proj_kernel(
    const bf16* __restrict__ X, const bf16* __restrict__ Wo,
    const bf16* __restrict__ bo, float* __restrict__ out) {
  gemm_bt_core<64, 128, 1, 4, float>(X, Wo, bo, out, 0);
}

// ---------------------------------------------------------------------------
// Flash attention v6: split-K (associative exp2 softmax), 1024 blocks.
// LDS = P(16 KB, stride 64 + XOR-8 chunk swizzle) + K(8 KB) + V(8 KB)
//     = 32768 B exactly -> 5 blocks/CU (launch_bounds 256,5; was 4).
// Q fragments loaded directly from global (one-time, L2-hot): no Q staging,
// no union, 2 fewer barriers.
// P addressing: elem (row q, col c) at row*64 + ((c>>3 ^ (row&7))<<3) + (c&7).
//   write banks: 2-way same-dword (free, m136); pf b128 reads: 8/bank (min).
// ---------------------------------------------------------------------------
__global__ __launch_bounds__(256, 5) void flash_kernel(
    const bf16* __restrict__ Qb, const bf16* __restrict__ Kb,
    const bf16* __restrict__ Vt, const int* __restrict__ mask,
    const unsigned char* __restrict__ msum, bf16* __restrict__ Op0,
    bf16* __restrict__ Op1, float* __restrict__ l0,
    float* __restrict__ l1) {
  const int flat = blockIdx.x;
  const int bh = flat & 31;
  const int kslice = (flat >> 5) & 1;
  const int qt = flat >> 6;  // 0..15 (128-row q tiles)
  const int b = bh >> 4;
  const int h = bh & 15;
  const int kb = kslice * (SS / 2);  // key-slice base

  bf16* Op = kslice ? Op1 : Op0;
  float* lp = kslice ? l1 : l0;

  const bf16* Qg = Qb + ((size_t)(b * SS + qt * 128)) * EE + h * 64;
  const bf16* Kg = Kb + ((size_t)(b * SS)) * EE + h * 64;
  const bf16* Vg = Vt + ((size_t)(b * HH + h)) * DKK * SS;

  __shared__ __align__(16) bf16 Ps[4 * 2048];  // per-wave P[32 q][64 key]
  __shared__ __align__(16) bf16 Ks[4096];
  __shared__ __align__(16) bf16 Vs[4096];

  const int tid = threadIdx.x;
  const int wid = tid >> 6, lane = tid & 63;
  const int lr = lane & 15, lg = lane >> 4;
  const int rchunk = (lg ^ (lr & 3)) * 8;  // K/V tile read swizzle

  // Q fragments straight from global (16B/lane x4; L2-hot, one-time)
  bf16x8 qf[2][2];
#pragma unroll
  for (int mi = 0; mi < 2; mi++)
#pragma unroll
    for (int kk = 0; kk < 2; kk++)
      qf[mi][kk] = *(const bf16x8*)(Qg +
          (size_t)(wid * 32 + mi * 16 + lr) * EE + kk * 32 + lg * 8);

  bf16x8 ones;
#pragma unroll
  for (int e = 0; e < 8; e++) ones[e] = (bf16)1.0f;

  f32x4 ot[2][4] = {};   // [mi][di]: rows q (lg*4+r), cols d (di*16+lr)
  f32x4 lacc[2] = {};    // [mi] row sums

  bf16* Pw = &Ps[wid * 2048];

  for (int kt = 0; kt < SS / 128; kt++) {  // 16 key-tiles of 64 in this slice
    const int kg = kb + kt * 64;
    const unsigned char sm = msum[(b * 16 + qt) * 32 + (kg >> 6)];
    if (sm == 0) continue;  // uniform per block

    // stage K (8 KB) + V^T (8 KB), XOR-4 swizzled
#pragma unroll
    for (int j = 0; j < 2; j++) {
      const int u = j * 256 + tid;
      const int kk = u >> 8, row = (u >> 2) & 63, c = u & 3;
      const int sc8 = (c ^ (row & 3)) * 8;
      ldg2lds16(Kg + (size_t)(kg + row) * EE + kk * 32 + sc8, &Ks[u * 8]);
      ldg2lds16(Vg + (size_t)row * SS + kg + kk * 32 + sc8, &Vs[u * 8]);
    }
    __syncthreads();

    // S' = QK' - 8 (shift folded into accumulator init); kf reused across mi
    f32x4 sc[2][4];
#pragma unroll
    for (int mi = 0; mi < 2; mi++)
#pragma unroll
      for (int ni = 0; ni < 4; ni++)
#pragma unroll
        for (int r = 0; r < 4; r++) sc[mi][ni][r] = -8.0f;
#pragma unroll
    for (int kk = 0; kk < 2; kk++)
#pragma unroll
      for (int ni = 0; ni < 4; ni++) {
        const bf16x8 kf =
            *(const bf16x8*)&Ks[kk * 2048 + (ni * 16 + lr) * 32 + rchunk];
#pragma unroll
        for (int mi = 0; mi < 2; mi++)
          sc[mi][ni] = __builtin_amdgcn_mfma_f32_16x16x32_bf16(
              qf[mi][kk], kf, sc[mi][ni], 0, 0, 0);
      }

    if (sm == 2) {  // mixed tile: masked -> 2^(-1e30) = 0
#pragma unroll
      for (int mi = 0; mi < 2; mi++)
#pragma unroll
        for (int ni = 0; ni < 4; ni++)
#pragma unroll
          for (int r = 0; r < 4; r++) {
            const int qq = qt * 128 + wid * 32 + mi * 16 + lg * 4 + r;
            const int kk2 = kg + ni * 16 + lr;
            if (mask[((size_t)b * SS + qq) * SS + kk2] == 0)
              sc[mi][ni][r] = -1e30f;
          }
    }

    // p = 2^sc ; per-wave P write, stride 64 + XOR-8 chunk swizzle
#pragma unroll
    for (int mi = 0; mi < 2; mi++)
#pragma unroll
      for (int ni = 0; ni < 4; ni++)
#pragma unroll
        for (int r = 0; r < 4; r++) {
          const int row = mi * 16 + lg * 4 + r;
          const int cch = (ni * 2 + (lr >> 3)) ^ (row & 7);
          Pw[row * 64 + cch * 8 + (lr & 7)] =
              (bf16)__builtin_amdgcn_exp2f(sc[mi][ni][r]);
        }

    // O += P*V ; l += P*1 ; vf reused across mi
#pragma unroll
    for (int kk = 0; kk < 2; kk++) {
      bf16x8 pf[2];
#pragma unroll
      for (int mi = 0; mi < 2; mi++) {
        const int row = mi * 16 + lr;
        pf[mi] = *(const bf16x8*)
            &Pw[row * 64 + (((kk * 4 + lg) ^ (row & 7)) << 3)];
        lacc[mi] = __builtin_amdgcn_mfma_f32_16x16x32_bf16(pf[mi], ones,
                                                           lacc[mi], 0, 0, 0);
      }
#pragma unroll
      for (int di = 0; di < 4; di++) {
        const bf16x8 vf =
            *(const bf16x8*)&Vs[kk * 2048 + (di * 16 + lr) * 32 + rchunk];
#pragma unroll
        for (int mi = 0; mi < 2; mi++)
          ot[mi][di] = __builtin_amdgcn_mfma_f32_16x16x32_bf16(
              pf[mi], vf, ot[mi][di], 0, 0, 0);
      }
    }
    __syncthreads();
  }

  // store partial O (bf16, unnormalized) and per-(row,head) l (fp32)
#pragma unroll
  for (int mi = 0; mi < 2; mi++) {
#pragma unroll
    for (int r = 0; r < 4; r++) {
      const int q = qt * 128 + wid * 32 + mi * 16 + lg * 4 + r;
      const size_t row = (size_t)b * SS + q;
      if (lr == 0) lp[row * HH + h] = lacc[mi][r];
      bf16* op = Op + row * EE + h * 64;
#pragma unroll
      for (int di = 0; di < 4; di++)
        op[di * 16 + lr] = (bf16)ot[mi][di][r];
    }
  }
}

// ---------------------------------------------------------------------------
// Combine: X[row][col] = (O0 + O1) / (l0[row,h] + l1[row,h]),  h = col>>6
// ---------------------------------------------------------------------------
__global__ __launch_bounds__(256) void combine_kernel(
    const bf16* __restrict__ Op0, const bf16* __restrict__ Op1,
    const float* __restrict__ l0, const float* __restrict__ l1,
    bf16* __restrict__ X) {
  const int i0 = (blockIdx.x * 256 + threadIdx.x) * 8;
  const int row = i0 >> 10;            // EE = 1024
  const int h = (i0 & 1023) >> 6;      // head of this 8-elem chunk
  const float l = l0[row * HH + h] + l1[row * HH + h];
  const float linv = (l > 0.f) ? 1.0f / l : 0.f;
  union { bf16 h8[8]; uint4 u; } a, b, o;
  a.u = *(const uint4*)(Op0 + i0);
  b.u = *(const uint4*)(Op1 + i0);
#pragma unroll
  for (int e = 0; e < 8; e++)
    o.h8[e] = (bf16)(((float)a.h8[e] + (float)b.h8[e]) * linv);
  *(uint4*)(X + i0) = o.u;
}

// ---------------------------------------------------------------------------
extern "C" void kernel_launch(void* const* d_in, const int* in_sizes, int n_in,
                              void* d_out, int out_size, void* d_ws,
                              size_t ws_size, hipStream_t stream) {
  const int* mask = (const int*)d_in[3];

  const size_t NIN = (size_t)BB * SS * EE;  // 4,194,304
  const size_t NW = (size_t)EE * EE;        // 1,048,576
  const size_t NRH = (size_t)BB * SS * HH;  // 65,536 (row,head) slots

  char* p = (char*)d_ws;
  // persistent-through-o_proj region first (NOT overlaid):
  bf16* cWo = (bf16*)p;  p += NW * 2;
  bf16* cb = (bf16*)p;   p += 4 * 1024 * 2;  // bq|bk|bv|bo
  unsigned char* msum = (unsigned char*)p; p += 1024;
  int* flag = (int*)p;   p += 1024;
  // region dead after qkv_proj -> overlaid by flash partials:
  char* ovl = p;
  bf16* cq = (bf16*)p;   p += NIN * 2;
  bf16* ck = (bf16*)p;   p += NIN * 2;
  bf16* cv = (bf16*)p;   p += NIN * 2;
  bf16* cWq = (bf16*)p;  p += NW * 2;
  bf16* cWk = (bf16*)p;  p += NW * 2;
  bf16* cWv = (bf16*)p;  p += NW * 2;
  // live after qkv:
  bf16* Qb = (bf16*)p;   p += NIN * 2;
  bf16* Kb = (bf16*)p;   p += NIN * 2;
  bf16* Vt = (bf16*)p;   p += NIN * 2;
  bf16* X = (bf16*)p;    p += NIN * 2;
  const size_t need = (size_t)(p - (char*)d_ws);
  if (ws_size < need) return;

  // overlay (16.5 MB into the 30 MB dead region):
  bf16* Op0 = (bf16*)ovl;
  bf16* Op1 = Op0 + NIN;
  float* l0 = (float*)(Op1 + NIN);
  float* l1 = l0 + NRH;

  detect_kernel<<<dim3(1), dim3(256), 0, stream>>>(
      (const unsigned int*)d_in[0], flag);

  ConvArgs ca;
  ca.src[0] = d_in[0];   ca.dst[0] = cq;        ca.n[0] = (int)NIN;
  ca.src[1] = d_in[1];   ca.dst[1] = ck;        ca.n[1] = (int)NIN;
  ca.src[2] = d_in[2];   ca.dst[2] = cv;        ca.n[2] = (int)NIN;
  ca.src[3] = d_in[4];   ca.dst[3] = cWq;       ca.n[3] = (int)NW;
  ca.src[4] = d_in[6];   ca.dst[4] = cWk;       ca.n[4] = (int)NW;
  ca.src[5] = d_in[8];   ca.dst[5] = cWv;       ca.n[5] = (int)NW;
  ca.src[6] = d_in[10];  ca.dst[6] = cWo;       ca.n[6] = (int)NW;
  ca.src[7] = d_in[5];   ca.dst[7] = cb;        ca.n[7] = 1024;
  ca.src[8] = d_in[7];   ca.dst[8] = cb + 1024; ca.n[8] = 1024;
  ca.src[9] = d_in[9];   ca.dst[9] = cb + 2048; ca.n[9] = 1024;
  ca.src[10] = d_in[11]; ca.dst[10] = cb + 3072; ca.n[10] = 1024;
  convert_kernel<<<dim3(2048, 11), dim3(256), 0, stream>>>(ca, flag);

  mask_summary_kernel<<<dim3(BB * 16 * 32), dim3(256), 0, stream>>>(mask, msum);

  qkv_proj_kernel<<<dim3(8, 32, 3), dim3(256), 0, stream>>>(
      cq, ck, cv, cWq, cWk, cWv, cb, Qb, Kb, Vt);

  flash_kernel<<<dim3(1024), dim3(256), 0, stream>>>(
      Qb, Kb, Vt, mask, msum, Op0, Op1, l0, l1);

  combine_kernel<<<dim3(2048), dim3(256), 0, stream>>>(Op0, Op1, l0, l1, X);

  o_proj_kernel<<<dim3(8, 64), dim3(256), 0, stream>>>(X, cWo, cb + 3072,
                                                       (float*)d_out);
}

// Round 12
// 286.351 us; speedup vs baseline: 1.5614x; 1.5614x over previous
//
#include <hip/hip_runtime.h>
#include <hip/hip_bf16.h>
#include <cstdint>
#include <cstddef>

#define BB 2
#define SS 2048
#define EE 1024
#define HH 16
#define DKK 64

typedef __bf16 bf16;
typedef __bf16 bf16x8 __attribute__((ext_vector_type(8)));
typedef float f32x4 __attribute__((ext_vector_type(4)));

__device__ __forceinline__ void ldg2lds16(const void* g, void* l) {
  __builtin_amdgcn_global_load_lds(
      (const __attribute__((address_space(1))) unsigned int*)g,
      (__attribute__((address_space(3))) unsigned int*)l, 16, 0, 0);
}

// ---------------------------------------------------------------------------
// Dtype detector (insurance): fp32 (flag=1) vs packed bf16 (flag=0).
// ---------------------------------------------------------------------------
__global__ __launch_bounds__(256) void detect_kernel(
    const unsigned int* __restrict__ q, int* __restrict__ flag) {
  const int t = threadIdx.x;
  int cnt = 0;
#pragma unroll
  for (int i = 0; i < 4; i++) {
    unsigned int v = q[t * 4 + i];
    unsigned int e = (v >> 7) & 0xFF;
    cnt += (e >= 110 && e <= 140) ? 1 : 0;
  }
  __shared__ int s;
  if (t == 0) s = 0;
  __syncthreads();
  atomicAdd(&s, cnt);
  __syncthreads();
  if (t == 0) *flag = (s < 512) ? 1 : 0;
}

// ---------------------------------------------------------------------------
// Convert prepass: materialize bf16 copies of all 11 float tensors.
// ---------------------------------------------------------------------------
struct ConvArgs {
  const void* src[11];
  void* dst[11];
  int n[11];
};

__global__ __launch_bounds__(256) void convert_kernel(
    ConvArgs a, const int* __restrict__ flag) {
  const int j = blockIdx.y;
  const int n = a.n[j];
  const int i0 = (blockIdx.x * 256 + threadIdx.x) * 8;
  if (i0 >= n) return;
  bf16* d = (bf16*)a.dst[j];
  if (*flag) {
    const float* s = (const float*)a.src[j];
    float4 f0 = ((const float4*)(s + i0))[0];
    float4 f1 = ((const float4*)(s + i0))[1];
    union { bf16 h[8]; uint4 u; } t;
    t.h[0] = (bf16)f0.x; t.h[1] = (bf16)f0.y;
    t.h[2] = (bf16)f0.z; t.h[3] = (bf16)f0.w;
    t.h[4] = (bf16)f1.x; t.h[5] = (bf16)f1.y;
    t.h[6] = (bf16)f1.z; t.h[7] = (bf16)f1.w;
    *(uint4*)(d + i0) = t.u;
  } else {
    uint4 v = *(const uint4*)((const bf16*)a.src[j] + i0);
    *(uint4*)(d + i0) = v;
  }
}

// ---------------------------------------------------------------------------
// Mask summary: per (b, q-tile-128, k-tile-64) -> 1 all-keep / 0 all-mask / 2 mixed
// ---------------------------------------------------------------------------
__global__ __launch_bounds__(256) void mask_summary_kernel(
    const int* __restrict__ mask, unsigned char* __restrict__ msum) {
  const int bid = blockIdx.x;            // b*512 + qt*32 + kt
  const int kt = bid & 31;
  const int qt = (bid >> 5) & 15;
  const int b = bid >> 9;
  const int t = threadIdx.x;
  const int r = t >> 1;
  const int c0 = (t & 1) * 32;
  const int* p = mask + ((size_t)(b * SS + qt * 128 + r)) * SS + kt * 64 + c0;
  bool all1 = true, any1 = false;
#pragma unroll
  for (int i = 0; i < 8; i++) {
    int4 v = ((const int4*)p)[i];
    all1 = all1 && (v.x != 0) && (v.y != 0) && (v.z != 0) && (v.w != 0);
    any1 = any1 || (v.x != 0) || (v.y != 0) || (v.z != 0) || (v.w != 0);
  }
  __shared__ int sall, sany;
  if (t == 0) { sall = 1; sany = 0; }
  __syncthreads();
  if (!all1) atomicAnd(&sall, 0);
  if (any1) atomicOr(&sany, 1);
  __syncthreads();
  if (t == 0) msum[bid] = sall ? 1 : (sany ? 2 : 0);
}

// ---------------------------------------------------------------------------
// bt-GEMM, BK=32 (r6/r7 winner), XOR swizzle.
// mode 0: row-major [M][1024]; mode 1: *0.125*log2e (Q pre-scale for exp2
// softmax); mode 2: transposed V write -> [B][H][DK][S].
// ---------------------------------------------------------------------------
template <int BM, int BN, int WGM, int WGN, typename OutT>
__device__ __forceinline__ void gemm_bt_core(
    const bf16* __restrict__ A, const bf16* __restrict__ W,
    const bf16* __restrict__ bias, OutT* __restrict__ out, int mode) {
  constexpr int BK = 32;
  constexpr int WM = BM / WGM, WN = BN / WGN;
  constexpr int MI = WM / 16, NI = WN / 16;
  constexpr int Kd = 1024, Nd = 1024;

  __shared__ __align__(16) bf16 As[BM * BK];
  __shared__ __align__(16) bf16 Bs[BN * BK];

  const int tid = threadIdx.x;
  const int wid = tid >> 6, lane = tid & 63;
  const int lr = lane & 15, lg = lane >> 4;
  const int wm = (wid / WGN) * WM, wn = (wid % WGN) * WN;
  const int m0 = blockIdx.y * BM, n0 = blockIdx.x * BN;

  f32x4 acc[MI][NI] = {};

  const int sr = tid >> 2;                        // staging row 0..63
  const int scol = ((tid & 3) ^ (sr & 3)) * 8;    // swizzled source chunk
  const int rchunk = (lg ^ (lr & 3)) * 8;         // swizzled read chunk

  for (int k0 = 0; k0 < Kd; k0 += BK) {
#pragma unroll
    for (int i = 0; i < BM / 64; i++)
      ldg2lds16(A + (size_t)(m0 + sr + i * 64) * Kd + k0 + scol,
                &As[(sr + i * 64) * BK + (tid & 3) * 8]);
#pragma unroll
    for (int i = 0; i < BN / 64; i++)
      ldg2lds16(W + (size_t)(n0 + sr + i * 64) * Kd + k0 + scol,
                &Bs[(sr + i * 64) * BK + (tid & 3) * 8]);
    __syncthreads();
    bf16x8 af[MI], bfr[NI];
#pragma unroll
    for (int mi = 0; mi < MI; mi++)
      af[mi] = *(const bf16x8*)&As[(wm + mi * 16 + lr) * BK + rchunk];
#pragma unroll
    for (int ni = 0; ni < NI; ni++)
      bfr[ni] = *(const bf16x8*)&Bs[(wn + ni * 16 + lr) * BK + rchunk];
#pragma unroll
    for (int mi = 0; mi < MI; mi++)
#pragma unroll
      for (int ni = 0; ni < NI; ni++)
        acc[mi][ni] = __builtin_amdgcn_mfma_f32_16x16x32_bf16(
            af[mi], bfr[ni], acc[mi][ni], 0, 0, 0);
    __syncthreads();
  }

  const float scale = (mode == 1) ? 0.180336880111f : 1.0f;  // 0.125*log2(e)

  // C/D layout: col = lane&15 (n), row = (lane>>4)*4 + reg (m)
#pragma unroll
  for (int ni = 0; ni < NI; ni++) {
    const int n = n0 + wn + ni * 16 + lr;
    const float bv = (float)bias[n];
#pragma unroll
    for (int mi = 0; mi < MI; mi++) {
      const int m = m0 + wm + mi * 16 + lg * 4;
      f32x4 v = acc[mi][ni];
      if (mode == 2) {
        const int h = n >> 6, d = n & 63;
        const int b = m >> 11, s0v = m & 2047;
        union { bf16 hh[4]; uint2 u; } tmp;
#pragma unroll
        for (int r = 0; r < 4; r++) tmp.hh[r] = (bf16)(v[r] + bv);
        const size_t idx = (((size_t)b * HH + h) * DKK + d) * SS + s0v;
        *(uint2*)((bf16*)out + idx) = tmp.u;
      } else {
#pragma unroll
        for (int r = 0; r < 4; r++)
          out[(size_t)(m + r) * Nd + n] = (OutT)((v[r] + bv) * scale);
      }
    }
  }
}

__global__ __launch_bounds__(256) void qkv_proj_kernel(
    const bf16* __restrict__ q, const bf16* __restrict__ k,
    const bf16* __restrict__ v, const bf16* __restrict__ Wq,
    const bf16* __restrict__ Wk, const bf16* __restrict__ Wv,
    const bf16* __restrict__ bias4, bf16* __restrict__ Qo,
    bf16* __restrict__ Ko, bf16* __restrict__ Vto) {
  const int z = blockIdx.z;
  const bf16* A = z == 0 ? q : (z == 1 ? k : v);
  const bf16* W = z == 0 ? Wq : (z == 1 ? Wk : Wv);
  const bf16* bi = bias4 + z * 1024;
  bf16* out = z == 0 ? Qo : (z == 1 ? Ko : Vto);
  gemm_bt_core<128, 128, 2, 2, bf16>(A, W, bi, out, z == 0 ? 1 : (z == 1 ? 0 : 2));
}

__global__ __launch_bounds__(256) void o_proj_kernel(
    const bf16* __restrict__ X, const bf16* __restrict__ Wo,
    const bf16* __restrict__ bo, float* __restrict__ out) {
  gemm_bt_core<64, 128, 1, 4, float>(X, Wo, bo, out, 0);
}

// ---------------------------------------------------------------------------
// Flash attention v6.1: split-K (associative exp2 softmax), 1024 blocks.
// launch_bounds (256,4): r11's (256,5) capped VGPR at 48 -> inner-loop scratch
// spill -> ~1 GB HBM traffic, 3x regression. 4 waves/EU leaves ~128 VGPR.
// LDS = P(16 KB, stride 64 + XOR-8) + K(8 KB) + V(8 KB) = 32768 B.
// Q fragments direct from global (one-time, L2-hot): no Q staging/barriers.
// ---------------------------------------------------------------------------
__global__ __launch_bounds__(256, 4) void flash_kernel(
    const bf16* __restrict__ Qb, const bf16* __restrict__ Kb,
    const bf16* __restrict__ Vt, const int* __restrict__ mask,
    const unsigned char* __restrict__ msum, bf16* __restrict__ Op0,
    bf16* __restrict__ Op1, float* __restrict__ l0,
    float* __restrict__ l1) {
  const int flat = blockIdx.x;
  const int bh = flat & 31;
  const int kslice = (flat >> 5) & 1;
  const int qt = flat >> 6;  // 0..15 (128-row q tiles)
  const int b = bh >> 4;
  const int h = bh & 15;
  const int kb = kslice * (SS / 2);  // key-slice base

  bf16* Op = kslice ? Op1 : Op0;
  float* lp = kslice ? l1 : l0;

  const bf16* Qg = Qb + ((size_t)(b * SS + qt * 128)) * EE + h * 64;
  const bf16* Kg = Kb + ((size_t)(b * SS)) * EE + h * 64;
  const bf16* Vg = Vt + ((size_t)(b * HH + h)) * DKK * SS;

  __shared__ __align__(16) bf16 Ps[4 * 2048];  // per-wave P[32 q][64 key]
  __shared__ __align__(16) bf16 Ks[4096];
  __shared__ __align__(16) bf16 Vs[4096];

  const int tid = threadIdx.x;
  const int wid = tid >> 6, lane = tid & 63;
  const int lr = lane & 15, lg = lane >> 4;
  const int rchunk = (lg ^ (lr & 3)) * 8;  // K/V tile read swizzle

  // Q fragments straight from global (16B/lane x4; L2-hot, one-time)
  bf16x8 qf[2][2];
#pragma unroll
  for (int mi = 0; mi < 2; mi++)
#pragma unroll
    for (int kk = 0; kk < 2; kk++)
      qf[mi][kk] = *(const bf16x8*)(Qg +
          (size_t)(wid * 32 + mi * 16 + lr) * EE + kk * 32 + lg * 8);

  bf16x8 ones;
#pragma unroll
  for (int e = 0; e < 8; e++) ones[e] = (bf16)1.0f;

  f32x4 ot[2][4] = {};   // [mi][di]: rows q (lg*4+r), cols d (di*16+lr)
  f32x4 lacc[2] = {};    // [mi] row sums

  bf16* Pw = &Ps[wid * 2048];

  for (int kt = 0; kt < SS / 128; kt++) {  // 16 key-tiles of 64 in this slice
    const int kg = kb + kt * 64;
    const unsigned char sm = msum[(b * 16 + qt) * 32 + (kg >> 6)];
    if (sm == 0) continue;  // uniform per block

    // stage K (8 KB) + V^T (8 KB), XOR-4 swizzled
#pragma unroll
    for (int j = 0; j < 2; j++) {
      const int u = j * 256 + tid;
      const int kk = u >> 8, row = (u >> 2) & 63, c = u & 3;
      const int sc8 = (c ^ (row & 3)) * 8;
      ldg2lds16(Kg + (size_t)(kg + row) * EE + kk * 32 + sc8, &Ks[u * 8]);
      ldg2lds16(Vg + (size_t)row * SS + kg + kk * 32 + sc8, &Vs[u * 8]);
    }
    __syncthreads();

    // S' = QK' - 8 (shift folded into accumulator init); kf reused across mi
    f32x4 sc[2][4];
#pragma unroll
    for (int mi = 0; mi < 2; mi++)
#pragma unroll
      for (int ni = 0; ni < 4; ni++)
#pragma unroll
        for (int r = 0; r < 4; r++) sc[mi][ni][r] = -8.0f;
#pragma unroll
    for (int kk = 0; kk < 2; kk++)
#pragma unroll
      for (int ni = 0; ni < 4; ni++) {
        const bf16x8 kf =
            *(const bf16x8*)&Ks[kk * 2048 + (ni * 16 + lr) * 32 + rchunk];
#pragma unroll
        for (int mi = 0; mi < 2; mi++)
          sc[mi][ni] = __builtin_amdgcn_mfma_f32_16x16x32_bf16(
              qf[mi][kk], kf, sc[mi][ni], 0, 0, 0);
      }

    if (sm == 2) {  // mixed tile: masked -> 2^(-1e30) = 0
#pragma unroll
      for (int mi = 0; mi < 2; mi++)
#pragma unroll
        for (int ni = 0; ni < 4; ni++)
#pragma unroll
          for (int r = 0; r < 4; r++) {
            const int qq = qt * 128 + wid * 32 + mi * 16 + lg * 4 + r;
            const int kk2 = kg + ni * 16 + lr;
            if (mask[((size_t)b * SS + qq) * SS + kk2] == 0)
              sc[mi][ni][r] = -1e30f;
          }
    }

    // p = 2^sc ; per-wave P write, stride 64 + XOR-8 chunk swizzle
#pragma unroll
    for (int mi = 0; mi < 2; mi++)
#pragma unroll
      for (int ni = 0; ni < 4; ni++)
#pragma unroll
        for (int r = 0; r < 4; r++) {
          const int row = mi * 16 + lg * 4 + r;
          const int cch = (ni * 2 + (lr >> 3)) ^ (row & 7);
          Pw[row * 64 + cch * 8 + (lr & 7)] =
              (bf16)__builtin_amdgcn_exp2f(sc[mi][ni][r]);
        }

    // O += P*V ; l += P*1 ; vf reused across mi
#pragma unroll
    for (int kk = 0; kk < 2; kk++) {
      bf16x8 pf[2];
#pragma unroll
      for (int mi = 0; mi < 2; mi++) {
        const int row = mi * 16 + lr;
        pf[mi] = *(const bf16x8*)
            &Pw[row * 64 + (((kk * 4 + lg) ^ (row & 7)) << 3)];
        lacc[mi] = __builtin_amdgcn_mfma_f32_16x16x32_bf16(pf[mi], ones,
                                                           lacc[mi], 0, 0, 0);
      }
#pragma unroll
      for (int di = 0; di < 4; di++) {
        const bf16x8 vf =
            *(const bf16x8*)&Vs[kk * 2048 + (di * 16 + lr) * 32 + rchunk];
#pragma unroll
        for (int mi = 0; mi < 2; mi++)
          ot[mi][di] = __builtin_amdgcn_mfma_f32_16x16x32_bf16(
              pf[mi], vf, ot[mi][di], 0, 0, 0);
      }
    }
    __syncthreads();
  }

  // store partial O (bf16, unnormalized) and per-(row,head) l (fp32)
#pragma unroll
  for (int mi = 0; mi < 2; mi++) {
#pragma unroll
    for (int r = 0; r < 4; r++) {
      const int q = qt * 128 + wid * 32 + mi * 16 + lg * 4 + r;
      const size_t row = (size_t)b * SS + q;
      if (lr == 0) lp[row * HH + h] = lacc[mi][r];
      bf16* op = Op + row * EE + h * 64;
#pragma unroll
      for (int di = 0; di < 4; di++)
        op[di * 16 + lr] = (bf16)ot[mi][di][r];
    }
  }
}

// ---------------------------------------------------------------------------
// Combine: X[row][col] = (O0 + O1) / (l0[row,h] + l1[row,h]),  h = col>>6
// ---------------------------------------------------------------------------
__global__ __launch_bounds__(256) void combine_kernel(
    const bf16* __restrict__ Op0, const bf16* __restrict__ Op1,
    const float* __restrict__ l0, const float* __restrict__ l1,
    bf16* __restrict__ X) {
  const int i0 = (blockIdx.x * 256 + threadIdx.x) * 8;
  const int row = i0 >> 10;            // EE = 1024
  const int h = (i0 & 1023) >> 6;      // head of this 8-elem chunk
  const float l = l0[row * HH + h] + l1[row * HH + h];
  const float linv = (l > 0.f) ? 1.0f / l : 0.f;
  union { bf16 h8[8]; uint4 u; } a, b, o;
  a.u = *(const uint4*)(Op0 + i0);
  b.u = *(const uint4*)(Op1 + i0);
#pragma unroll
  for (int e = 0; e < 8; e++)
    o.h8[e] = (bf16)(((float)a.h8[e] + (float)b.h8[e]) * linv);
  *(uint4*)(X + i0) = o.u;
}

// ---------------------------------------------------------------------------
extern "C" void kernel_launch(void* const* d_in, const int* in_sizes, int n_in,
                              void* d_out, int out_size, void* d_ws,
                              size_t ws_size, hipStream_t stream) {
  const int* mask = (const int*)d_in[3];

  const size_t NIN = (size_t)BB * SS * EE;  // 4,194,304
  const size_t NW = (size_t)EE * EE;        // 1,048,576
  const size_t NRH = (size_t)BB * SS * HH;  // 65,536 (row,head) slots

  char* p = (char*)d_ws;
  // persistent-through-o_proj region first (NOT overlaid):
  bf16* cWo = (bf16*)p;  p += NW * 2;
  bf16* cb = (bf16*)p;   p += 4 * 1024 * 2;  // bq|bk|bv|bo
  unsigned char* msum = (unsigned char*)p; p += 1024;
  int* flag = (int*)p;   p += 1024;
  // region dead after qkv_proj -> overlaid by flash partials:
  char* ovl = p;
  bf16* cq = (bf16*)p;   p += NIN * 2;
  bf16* ck = (bf16*)p;   p += NIN * 2;
  bf16* cv = (bf16*)p;   p += NIN * 2;
  bf16* cWq = (bf16*)p;  p += NW * 2;
  bf16* cWk = (bf16*)p;  p += NW * 2;
  bf16* cWv = (bf16*)p;  p += NW * 2;
  // live after qkv:
  bf16* Qb = (bf16*)p;   p += NIN * 2;
  bf16* Kb = (bf16*)p;   p += NIN * 2;
  bf16* Vt = (bf16*)p;   p += NIN * 2;
  bf16* X = (bf16*)p;    p += NIN * 2;
  const size_t need = (size_t)(p - (char*)d_ws);
  if (ws_size < need) return;

  // overlay (16.5 MB into the 30 MB dead region):
  bf16* Op0 = (bf16*)ovl;
  bf16* Op1 = Op0 + NIN;
  float* l0 = (float*)(Op1 + NIN);
  float* l1 = l0 + NRH;

  detect_kernel<<<dim3(1), dim3(256), 0, stream>>>(
      (const unsigned int*)d_in[0], flag);

  ConvArgs ca;
  ca.src[0] = d_in[0];   ca.dst[0] = cq;        ca.n[0] = (int)NIN;
  ca.src[1] = d_in[1];   ca.dst[1] = ck;        ca.n[1] = (int)NIN;
  ca.src[2] = d_in[2];   ca.dst[2] = cv;        ca.n[2] = (int)NIN;
  ca.src[3] = d_in[4];   ca.dst[3] = cWq;       ca.n[3] = (int)NW;
  ca.src[4] = d_in[6];   ca.dst[4] = cWk;       ca.n[4] = (int)NW;
  ca.src[5] = d_in[8];   ca.dst[5] = cWv;       ca.n[5] = (int)NW;
  ca.src[6] = d_in[10];  ca.dst[6] = cWo;       ca.n[6] = (int)NW;
  ca.src[7] = d_in[5];   ca.dst[7] = cb;        ca.n[7] = 1024;
  ca.src[8] = d_in[7];   ca.dst[8] = cb + 1024; ca.n[8] = 1024;
  ca.src[9] = d_in[9];   ca.dst[9] = cb + 2048; ca.n[9] = 1024;
  ca.src[10] = d_in[11]; ca.dst[10] = cb + 3072; ca.n[10] = 1024;
  convert_kernel<<<dim3(2048, 11), dim3(256), 0, stream>>>(ca, flag);

  mask_summary_kernel<<<dim3(BB * 16 * 32), dim3(256), 0, stream>>>(mask, msum);

  qkv_proj_kernel<<<dim3(8, 32, 3), dim3(256), 0, stream>>>(
      cq, ck, cv, cWq, cWk, cWv, cb, Qb, Kb, Vt);

  flash_kernel<<<dim3(1024), dim3(256), 0, stream>>>(
      Qb, Kb, Vt, mask, msum, Op0, Op1, l0, l1);

  combine_kernel<<<dim3(2048), dim3(256), 0, stream>>>(Op0, Op1, l0, l1, X);

  o_proj_kernel<<<dim3(8, 64), dim3(256), 0, stream>>>(X, cWo, cb + 3072,
                                                       (float*)d_out);
}

// Round 13
// 264.088 us; speedup vs baseline: 1.6931x; 1.0843x over previous
//
#include <hip/hip_runtime.h>
#include <hip/hip_bf16.h>
#include <cstdint>
#include <cstddef>

#define BB 2
#define SS 2048
#define EE 1024
#define HH 16
#define DKK 64

typedef __bf16 bf16;
typedef __bf16 bf16x8 __attribute__((ext_vector_type(8)));
typedef float f32x4 __attribute__((ext_vector_type(4)));

__device__ __forceinline__ void ldg2lds16(const void* g, void* l) {
  __builtin_amdgcn_global_load_lds(
      (const __attribute__((address_space(1))) unsigned int*)g,
      (__attribute__((address_space(3))) unsigned int*)l, 16, 0, 0);
}

// ---------------------------------------------------------------------------
// Dtype detector (insurance): fp32 (flag=1) vs packed bf16 (flag=0).
// ---------------------------------------------------------------------------
__global__ __launch_bounds__(256) void detect_kernel(
    const unsigned int* __restrict__ q, int* __restrict__ flag) {
  const int t = threadIdx.x;
  int cnt = 0;
#pragma unroll
  for (int i = 0; i < 4; i++) {
    unsigned int v = q[t * 4 + i];
    unsigned int e = (v >> 7) & 0xFF;
    cnt += (e >= 110 && e <= 140) ? 1 : 0;
  }
  __shared__ int s;
  if (t == 0) s = 0;
  __syncthreads();
  atomicAdd(&s, cnt);
  __syncthreads();
  if (t == 0) *flag = (s < 512) ? 1 : 0;
}

// ---------------------------------------------------------------------------
// Convert prepass: materialize bf16 copies of all 11 float tensors.
// ---------------------------------------------------------------------------
struct ConvArgs {
  const void* src[11];
  void* dst[11];
  int n[11];
};

__global__ __launch_bounds__(256) void convert_kernel(
    ConvArgs a, const int* __restrict__ flag) {
  const int j = blockIdx.y;
  const int n = a.n[j];
  const int i0 = (blockIdx.x * 256 + threadIdx.x) * 8;
  if (i0 >= n) return;
  bf16* d = (bf16*)a.dst[j];
  if (*flag) {
    const float* s = (const float*)a.src[j];
    float4 f0 = ((const float4*)(s + i0))[0];
    float4 f1 = ((const float4*)(s + i0))[1];
    union { bf16 h[8]; uint4 u; } t;
    t.h[0] = (bf16)f0.x; t.h[1] = (bf16)f0.y;
    t.h[2] = (bf16)f0.z; t.h[3] = (bf16)f0.w;
    t.h[4] = (bf16)f1.x; t.h[5] = (bf16)f1.y;
    t.h[6] = (bf16)f1.z; t.h[7] = (bf16)f1.w;
    *(uint4*)(d + i0) = t.u;
  } else {
    uint4 v = *(const uint4*)((const bf16*)a.src[j] + i0);
    *(uint4*)(d + i0) = v;
  }
}

// ---------------------------------------------------------------------------
// Mask summary: per (b, q-tile-128, k-tile-64) -> 1 all-keep / 0 all-mask / 2 mixed
// ---------------------------------------------------------------------------
__global__ __launch_bounds__(256) void mask_summary_kernel(
    const int* __restrict__ mask, unsigned char* __restrict__ msum) {
  const int bid = blockIdx.x;            // b*512 + qt*32 + kt
  const int kt = bid & 31;
  const int qt = (bid >> 5) & 15;
  const int b = bid >> 9;
  const int t = threadIdx.x;
  const int r = t >> 1;
  const int c0 = (t & 1) * 32;
  const int* p = mask + ((size_t)(b * SS + qt * 128 + r)) * SS + kt * 64 + c0;
  bool all1 = true, any1 = false;
#pragma unroll
  for (int i = 0; i < 8; i++) {
    int4 v = ((const int4*)p)[i];
    all1 = all1 && (v.x != 0) && (v.y != 0) && (v.z != 0) && (v.w != 0);
    any1 = any1 || (v.x != 0) || (v.y != 0) || (v.z != 0) || (v.w != 0);
  }
  __shared__ int sall, sany;
  if (t == 0) { sall = 1; sany = 0; }
  __syncthreads();
  if (!all1) atomicAnd(&sall, 0);
  if (any1) atomicOr(&sany, 1);
  __syncthreads();
  if (t == 0) msum[bid] = sall ? 1 : (sany ? 2 : 0);
}

// ---------------------------------------------------------------------------
// bt-GEMM, BK=32, XOR swizzle. C[m][n] = sum_k A[m][k]*W[n][k] (+ bias).
// mode 0: col-bias; mode 1: col-bias, *0.125*log2e (Q pre-scale);
// mode 3: ROW-bias (for Vt = Wv x value^T, out [1024][4096]).
// ND = out leading dimension. m0/n0 passed by caller (grid-axis flexibility).
// ---------------------------------------------------------------------------
template <int BM, int BN, int WGM, int WGN, int ND, typename OutT>
__device__ __forceinline__ void gemm_bt_core(
    const bf16* __restrict__ A, const bf16* __restrict__ W,
    const bf16* __restrict__ bias, OutT* __restrict__ out, int mode,
    int m0, int n0) {
  constexpr int BK = 32;
  constexpr int WM = BM / WGM, WN = BN / WGN;
  constexpr int MI = WM / 16, NI = WN / 16;
  constexpr int Kd = 1024;

  __shared__ __align__(16) bf16 As[BM * BK];
  __shared__ __align__(16) bf16 Bs[BN * BK];

  const int tid = threadIdx.x;
  const int wid = tid >> 6, lane = tid & 63;
  const int lr = lane & 15, lg = lane >> 4;
  const int wm = (wid / WGN) * WM, wn = (wid % WGN) * WN;

  f32x4 acc[MI][NI] = {};

  const int sr = tid >> 2;                        // staging row 0..63
  const int scol = ((tid & 3) ^ (sr & 3)) * 8;    // swizzled source chunk
  const int rchunk = (lg ^ (lr & 3)) * 8;         // swizzled read chunk

  for (int k0 = 0; k0 < Kd; k0 += BK) {
#pragma unroll
    for (int i = 0; i < BM / 64; i++)
      ldg2lds16(A + (size_t)(m0 + sr + i * 64) * Kd + k0 + scol,
                &As[(sr + i * 64) * BK + (tid & 3) * 8]);
#pragma unroll
    for (int i = 0; i < BN / 64; i++)
      ldg2lds16(W + (size_t)(n0 + sr + i * 64) * Kd + k0 + scol,
                &Bs[(sr + i * 64) * BK + (tid & 3) * 8]);
    __syncthreads();
    bf16x8 af[MI], bfr[NI];
#pragma unroll
    for (int mi = 0; mi < MI; mi++)
      af[mi] = *(const bf16x8*)&As[(wm + mi * 16 + lr) * BK + rchunk];
#pragma unroll
    for (int ni = 0; ni < NI; ni++)
      bfr[ni] = *(const bf16x8*)&Bs[(wn + ni * 16 + lr) * BK + rchunk];
#pragma unroll
    for (int mi = 0; mi < MI; mi++)
#pragma unroll
      for (int ni = 0; ni < NI; ni++)
        acc[mi][ni] = __builtin_amdgcn_mfma_f32_16x16x32_bf16(
            af[mi], bfr[ni], acc[mi][ni], 0, 0, 0);
    __syncthreads();
  }

  const float scale = (mode == 1) ? 0.180336880111f : 1.0f;  // 0.125*log2(e)

  // C/D layout: col = lane&15 (n), row = (lane>>4)*4 + reg (m)
#pragma unroll
  for (int ni = 0; ni < NI; ni++) {
    const int n = n0 + wn + ni * 16 + lr;
    const float bvc = (mode == 3) ? 0.f : (float)bias[n];
#pragma unroll
    for (int mi = 0; mi < MI; mi++) {
      const int m = m0 + wm + mi * 16 + lg * 4;
      f32x4 v = acc[mi][ni];
#pragma unroll
      for (int r = 0; r < 4; r++) {
        const float bv = (mode == 3) ? (float)bias[m + r] : bvc;
        out[(size_t)(m + r) * ND + n] = (OutT)((v[r] + bv) * scale);
      }
    }
  }
}

__global__ __launch_bounds__(256) void qkv_proj_kernel(
    const bf16* __restrict__ q, const bf16* __restrict__ k,
    const bf16* __restrict__ v, const bf16* __restrict__ Wq,
    const bf16* __restrict__ Wk, const bf16* __restrict__ Wv,
    const bf16* __restrict__ bias4, bf16* __restrict__ Qo,
    bf16* __restrict__ Ko, bf16* __restrict__ Vto) {
  const int z = blockIdx.z;
  if (z == 2) {
    // Vt[(h*64+d)][(b*2048+s)] = Wv (A-rows) x value (W-rows); row-bias bv.
    gemm_bt_core<128, 128, 2, 2, 4096, bf16>(
        Wv, v, bias4 + 2 * 1024, Vto, 3, blockIdx.x * 128, blockIdx.y * 128);
  } else {
    const bf16* A = z == 0 ? q : k;
    const bf16* W = z == 0 ? Wq : Wk;
    bf16* out = z == 0 ? Qo : Ko;
    gemm_bt_core<128, 128, 2, 2, 1024, bf16>(
        A, W, bias4 + z * 1024, out, z == 0 ? 1 : 0, blockIdx.y * 128,
        blockIdx.x * 128);
  }
}

__global__ __launch_bounds__(256) void o_proj_kernel(
    const bf16* __restrict__ X, const bf16* __restrict__ Wo,
    const bf16* __restrict__ bo, float* __restrict__ out) {
  gemm_bt_core<64, 128, 1, 4, 1024, float>(X, Wo, bo, out, 0,
                                           blockIdx.y * 64, blockIdx.x * 128);
}

// ---------------------------------------------------------------------------
// Flash attention v7: split-K (associative exp2 softmax), 1024 blocks,
// launch_bounds (256,4) [(256,5) spills -> 1 GB scratch, r11].
// LDS: Ps 16 KB (transient Q staging union) + Ks 8 KB + Vs 8 KB = 32 KB.
// QK^T restructured ni-outer: sc live = 8 regs (was 32) -> no qf remat/spill
// (r12 FETCH showed +43 MB of per-iteration Q re-loads at VGPR=64).
// Vt layout now [H*DK][B*S] (direct from qkv mode-3 GEMM), row stride 4096.
// ---------------------------------------------------------------------------
__global__ __launch_bounds__(256, 4) void flash_kernel(
    const bf16* __restrict__ Qb, const bf16* __restrict__ Kb,
    const bf16* __restrict__ Vt, const int* __restrict__ mask,
    const unsigned char* __restrict__ msum, bf16* __restrict__ Op0,
    bf16* __restrict__ Op1, float* __restrict__ l0,
    float* __restrict__ l1) {
  const int flat = blockIdx.x;
  const int bh = flat & 31;
  const int kslice = (flat >> 5) & 1;
  const int qt = flat >> 6;  // 0..15 (128-row q tiles)
  const int b = bh >> 4;
  const int h = bh & 15;
  const int kb = kslice * (SS / 2);  // key-slice base

  bf16* Op = kslice ? Op1 : Op0;
  float* lp = kslice ? l1 : l0;

  const bf16* Qg = Qb + ((size_t)(b * SS + qt * 128)) * EE + h * 64;
  const bf16* Kg = Kb + ((size_t)(b * SS)) * EE + h * 64;
  const bf16* Vg = Vt + (size_t)(h * 64) * (BB * SS) + b * SS;

  __shared__ __align__(16) bf16 Ps[4 * 2048];  // P[32q][64key]; Q staging union
  __shared__ __align__(16) bf16 Ks[4096];
  __shared__ __align__(16) bf16 Vs[4096];

  const int tid = threadIdx.x;
  const int wid = tid >> 6, lane = tid & 63;
  const int lr = lane & 15, lg = lane >> 4;
  const int rchunk = (lg ^ (lr & 3)) * 8;  // K/V/Q tile read swizzle

  // stage Q (16 KB exactly = Ps) as [kk][row128][32], XOR-4 swizzled
#pragma unroll
  for (int j = 0; j < 4; j++) {
    const int u = j * 256 + tid;
    const int kk = u >> 9, row = (u >> 2) & 127, c = u & 3;
    ldg2lds16(Qg + (size_t)row * EE + kk * 32 + ((c ^ (row & 3)) * 8),
              &Ps[u * 8]);
  }
  __syncthreads();

  bf16x8 qf[2][2];
#pragma unroll
  for (int mi = 0; mi < 2; mi++)
#pragma unroll
    for (int kk = 0; kk < 2; kk++)
      qf[mi][kk] = *(const bf16x8*)
          &Ps[kk * 4096 + (wid * 32 + mi * 16 + lr) * 32 + rchunk];
  __syncthreads();  // drain qf reads before P overwrites this space

  bf16x8 ones;
#pragma unroll
  for (int e = 0; e < 8; e++) ones[e] = (bf16)1.0f;

  f32x4 ot[2][4] = {};   // [mi][di]: rows q (lg*4+r), cols d (di*16+lr)
  f32x4 lacc[2] = {};    // [mi] row sums

  bf16* Pw = &Ps[wid * 2048];

  for (int kt = 0; kt < SS / 128; kt++) {  // 16 key-tiles of 64 in this slice
    const int kg = kb + kt * 64;
    const unsigned char sm = msum[(b * 16 + qt) * 32 + (kg >> 6)];
    if (sm == 0) continue;  // uniform per block

    // stage K (8 KB) + V^T (8 KB), XOR-4 swizzled
#pragma unroll
    for (int j = 0; j < 2; j++) {
      const int u = j * 256 + tid;
      const int kk = u >> 8, row = (u >> 2) & 63, c = u & 3;
      const int sc8 = (c ^ (row & 3)) * 8;
      ldg2lds16(Kg + (size_t)(kg + row) * EE + kk * 32 + sc8, &Ks[u * 8]);
      ldg2lds16(Vg + (size_t)row * (BB * SS) + kg + kk * 32 + sc8, &Vs[u * 8]);
    }
    __syncthreads();

    // S' = QK' - 8; ni-outer so sc lives only 8 regs -> no spill/remat
#pragma unroll
    for (int ni = 0; ni < 4; ni++) {
      f32x4 sc[2];
#pragma unroll
      for (int mi = 0; mi < 2; mi++)
#pragma unroll
        for (int r = 0; r < 4; r++) sc[mi][r] = -8.0f;
#pragma unroll
      for (int kk = 0; kk < 2; kk++) {
        const bf16x8 kf =
            *(const bf16x8*)&Ks[kk * 2048 + (ni * 16 + lr) * 32 + rchunk];
#pragma unroll
        for (int mi = 0; mi < 2; mi++)
          sc[mi] = __builtin_amdgcn_mfma_f32_16x16x32_bf16(qf[mi][kk], kf,
                                                           sc[mi], 0, 0, 0);
      }
      if (sm == 2) {  // mixed tile: masked -> 2^(-1e30) = 0
#pragma unroll
        for (int mi = 0; mi < 2; mi++)
#pragma unroll
          for (int r = 0; r < 4; r++) {
            const int qq = qt * 128 + wid * 32 + mi * 16 + lg * 4 + r;
            const int kk2 = kg + ni * 16 + lr;
            if (mask[((size_t)b * SS + qq) * SS + kk2] == 0)
              sc[mi][r] = -1e30f;
          }
      }
      // p = 2^sc ; P write, stride 64 + XOR-8 chunk swizzle
#pragma unroll
      for (int mi = 0; mi < 2; mi++)
#pragma unroll
        for (int r = 0; r < 4; r++) {
          const int row = mi * 16 + lg * 4 + r;
          const int cch = (ni * 2 + (lr >> 3)) ^ (row & 7);
          Pw[row * 64 + cch * 8 + (lr & 7)] =
              (bf16)__builtin_amdgcn_exp2f(sc[mi][r]);
        }
    }

    // O += P*V ; l += P*1 (same-wave P RAW ordered via lgkmcnt)
#pragma unroll
    for (int kk = 0; kk < 2; kk++) {
      bf16x8 pf[2];
#pragma unroll
      for (int mi = 0; mi < 2; mi++) {
        const int row = mi * 16 + lr;
        pf[mi] = *(const bf16x8*)
            &Pw[row * 64 + (((kk * 4 + lg) ^ (row & 7)) << 3)];
        lacc[mi] = __builtin_amdgcn_mfma_f32_16x16x32_bf16(pf[mi], ones,
                                                           lacc[mi], 0, 0, 0);
      }
#pragma unroll
      for (int di = 0; di < 4; di++) {
        const bf16x8 vf =
            *(const bf16x8*)&Vs[kk * 2048 + (di * 16 + lr) * 32 + rchunk];
#pragma unroll
        for (int mi = 0; mi < 2; mi++)
          ot[mi][di] = __builtin_amdgcn_mfma_f32_16x16x32_bf16(
              pf[mi], vf, ot[mi][di], 0, 0, 0);
      }
    }
    __syncthreads();
  }

  // store partial O (bf16, unnormalized) and per-(row,head) l (fp32)
#pragma unroll
  for (int mi = 0; mi < 2; mi++) {
#pragma unroll
    for (int r = 0; r < 4; r++) {
      const int q = qt * 128 + wid * 32 + mi * 16 + lg * 4 + r;
      const size_t row = (size_t)b * SS + q;
      if (lr == 0) lp[row * HH + h] = lacc[mi][r];
      bf16* op = Op + row * EE + h * 64;
#pragma unroll
      for (int di = 0; di < 4; di++)
        op[di * 16 + lr] = (bf16)ot[mi][di][r];
    }
  }
}

// ---------------------------------------------------------------------------
// Combine: X[row][col] = (O0 + O1) / (l0[row,h] + l1[row,h]),  h = col>>6
// ---------------------------------------------------------------------------
__global__ __launch_bounds__(256) void combine_kernel(
    const bf16* __restrict__ Op0, const bf16* __restrict__ Op1,
    const float* __restrict__ l0, const float* __restrict__ l1,
    bf16* __restrict__ X) {
  const int i0 = (blockIdx.x * 256 + threadIdx.x) * 8;
  const int row = i0 >> 10;            // EE = 1024
  const int h = (i0 & 1023) >> 6;      // head of this 8-elem chunk
  const float l = l0[row * HH + h] + l1[row * HH + h];
  const float linv = (l > 0.f) ? 1.0f / l : 0.f;
  union { bf16 h8[8]; uint4 u; } a, b, o;
  a.u = *(const uint4*)(Op0 + i0);
  b.u = *(const uint4*)(Op1 + i0);
#pragma unroll
  for (int e = 0; e < 8; e++)
    o.h8[e] = (bf16)(((float)a.h8[e] + (float)b.h8[e]) * linv);
  *(uint4*)(X + i0) = o.u;
}

// ---------------------------------------------------------------------------
extern "C" void kernel_launch(void* const* d_in, const int* in_sizes, int n_in,
                              void* d_out, int out_size, void* d_ws,
                              size_t ws_size, hipStream_t stream) {
  const int* mask = (const int*)d_in[3];

  const size_t NIN = (size_t)BB * SS * EE;  // 4,194,304
  const size_t NW = (size_t)EE * EE;        // 1,048,576
  const size_t NRH = (size_t)BB * SS * HH;  // 65,536 (row,head) slots

  char* p = (char*)d_ws;
  // persistent-through-o_proj region first (NOT overlaid):
  bf16* cWo = (bf16*)p;  p += NW * 2;
  bf16* cb = (bf16*)p;   p += 4 * 1024 * 2;  // bq|bk|bv|bo
  unsigned char* msum = (unsigned char*)p; p += 1024;
  int* flag = (int*)p;   p += 1024;
  // region dead after qkv_proj -> overlaid by flash partials:
  char* ovl = p;
  bf16* cq = (bf16*)p;   p += NIN * 2;
  bf16* ck = (bf16*)p;   p += NIN * 2;
  bf16* cv = (bf16*)p;   p += NIN * 2;
  bf16* cWq = (bf16*)p;  p += NW * 2;
  bf16* cWk = (bf16*)p;  p += NW * 2;
  bf16* cWv = (bf16*)p;  p += NW * 2;
  // live after qkv:
  bf16* Qb = (bf16*)p;   p += NIN * 2;
  bf16* Kb = (bf16*)p;   p += NIN * 2;
  bf16* Vt = (bf16*)p;   p += NIN * 2;
  bf16* X = (bf16*)p;    p += NIN * 2;
  const size_t need = (size_t)(p - (char*)d_ws);
  if (ws_size < need) return;

  // overlay (16.5 MB into the 30 MB dead region):
  bf16* Op0 = (bf16*)ovl;
  bf16* Op1 = Op0 + NIN;
  float* l0 = (float*)(Op1 + NIN);
  float* l1 = l0 + NRH;

  detect_kernel<<<dim3(1), dim3(256), 0, stream>>>(
      (const unsigned int*)d_in[0], flag);

  ConvArgs ca;
  ca.src[0] = d_in[0];   ca.dst[0] = cq;        ca.n[0] = (int)NIN;
  ca.src[1] = d_in[1];   ca.dst[1] = ck;        ca.n[1] = (int)NIN;
  ca.src[2] = d_in[2];   ca.dst[2] = cv;        ca.n[2] = (int)NIN;
  ca.src[3] = d_in[4];   ca.dst[3] = cWq;       ca.n[3] = (int)NW;
  ca.src[4] = d_in[6];   ca.dst[4] = cWk;       ca.n[4] = (int)NW;
  ca.src[5] = d_in[8];   ca.dst[5] = cWv;       ca.n[5] = (int)NW;
  ca.src[6] = d_in[10];  ca.dst[6] = cWo;       ca.n[6] = (int)NW;
  ca.src[7] = d_in[5];   ca.dst[7] = cb;        ca.n[7] = 1024;
  ca.src[8] = d_in[7];   ca.dst[8] = cb + 1024; ca.n[8] = 1024;
  ca.src[9] = d_in[9];   ca.dst[9] = cb + 2048; ca.n[9] = 1024;
  ca.src[10] = d_in[11]; ca.dst[10] = cb + 3072; ca.n[10] = 1024;
  convert_kernel<<<dim3(2048, 11), dim3(256), 0, stream>>>(ca, flag);

  mask_summary_kernel<<<dim3(BB * 16 * 32), dim3(256), 0, stream>>>(mask, msum);

  qkv_proj_kernel<<<dim3(8, 32, 3), dim3(256), 0, stream>>>(
      cq, ck, cv, cWq, cWk, cWv, cb, Qb, Kb, Vt);

  flash_kernel<<<dim3(1024), dim3(256), 0, stream>>>(
      Qb, Kb, Vt, mask, msum, Op0, Op1, l0, l1);

  combine_kernel<<<dim3(2048), dim3(256), 0, stream>>>(Op0, Op1, l0, l1, X);

  o_proj_kernel<<<dim3(8, 64), dim3(256), 0, stream>>>(X, cWo, cb + 3072,
                                                       (float*)d_out);
}